// Round 1
// baseline (685.572 us; speedup 1.0000x reference)
//
#include <hip/hip_runtime.h>
#include <hip/hip_bf16.h>
#include <math.h>

static inline size_t align_up(size_t x, size_t a) { return (x + a - 1) / a * a; }

// ---------------- CSR build ----------------

__global__ void hist_kernel(const int* __restrict__ dst, int* __restrict__ cnt, int e) {
  int i = blockIdx.x * blockDim.x + threadIdx.x;
  if (i < e) atomicAdd(&cnt[dst[i]], 1);
}

__global__ __launch_bounds__(256) void scanA_kernel(const int* __restrict__ cnt,
                                                    int* __restrict__ excl,
                                                    int* __restrict__ bsum, int n) {
  __shared__ int sm[256];
  int gi = blockIdx.x * 256 + threadIdx.x;
  int v = (gi < n) ? cnt[gi] : 0;
  sm[threadIdx.x] = v;
  __syncthreads();
  for (int off = 1; off < 256; off <<= 1) {
    int x = (threadIdx.x >= off) ? sm[threadIdx.x - off] : 0;
    __syncthreads();
    sm[threadIdx.x] += x;
    __syncthreads();
  }
  if (gi < n) excl[gi] = sm[threadIdx.x] - v;
  if (threadIdx.x == 255) bsum[blockIdx.x] = sm[255];
}

__global__ __launch_bounds__(512) void scanB_kernel(int* __restrict__ bsum, int nb) {
  __shared__ int sm[512];
  const int t = threadIdx.x;
  int v = (t < nb) ? bsum[t] : 0;
  sm[t] = v;
  __syncthreads();
  for (int off = 1; off < 512; off <<= 1) {
    int x = (t >= off) ? sm[t - off] : 0;
    __syncthreads();
    sm[t] += x;
    __syncthreads();
  }
  if (t < nb) bsum[t] = sm[t] - v;  // exclusive block offsets
}

__global__ void scanC_kernel(int* __restrict__ rowptr, const int* __restrict__ bsum,
                             int n, int e) {
  int gi = blockIdx.x * 256 + threadIdx.x;
  if (gi < n) rowptr[gi] += bsum[blockIdx.x];
  if (gi == 0) rowptr[n] = e;
}

__global__ void dinv_kernel(const int* __restrict__ rowptr, float* __restrict__ dinv, int n) {
  int gi = blockIdx.x * blockDim.x + threadIdx.x;
  if (gi < n) dinv[gi] = rsqrtf((float)(rowptr[gi + 1] - rowptr[gi] + 1));
}

__global__ void fill_kernel(const int* __restrict__ src, const int* __restrict__ dst,
                            const int* __restrict__ rowptr, int* __restrict__ cur,
                            const float* __restrict__ dinv, int* __restrict__ ssrc,
                            float* __restrict__ wnorm, int e) {
  int i = blockIdx.x * blockDim.x + threadIdx.x;
  if (i < e) {
    int d = dst[i];
    int s = src[i];
    int pos = rowptr[d] + atomicAdd(&cur[d], 1);
    ssrc[pos] = s;
    wnorm[pos] = dinv[s] * dinv[d];
  }
}

// ---------------- GEMM: out[N][128] = A(concat x|emb[drnl] or z)[N][K] @ W[K][128] ----------------
// block 256 threads, tile 64 rows x 128 cols, BK=16.
// per thread: 8 rows x 4 cols.

__global__ __launch_bounds__(256) void gemm_kernel(
    const float* __restrict__ A, const float* __restrict__ emb,
    const int* __restrict__ drnl, const float* __restrict__ W,
    float* __restrict__ out, int n, int K) {
  __shared__ float As[16][68];   // k-major, padded
  __shared__ float Bs[16][128];
  const int tid = threadIdx.x;
  const int row0 = blockIdx.x * 64;
  const int tc = (tid & 31) * 4;   // col base
  const int tr = (tid >> 5) * 8;   // row base

  float acc[8][4];
#pragma unroll
  for (int i = 0; i < 8; ++i)
#pragma unroll
    for (int j = 0; j < 4; ++j) acc[i][j] = 0.f;

  const int lrow = tid >> 2;        // 0..63 — A-load row
  const int lk = (tid & 3) * 4;     // 0,4,8,12 — A-load k base
  const int grow = row0 + lrow;
  const bool rowok = grow < n;
  int embrow = 0;
  if (K > 128 && rowok) embrow = drnl[grow];

  const int bk = tid >> 4;          // 0..15 — B-load row
  const int bc = (tid & 15) * 8;    // B-load col base

  const int nk = K >> 4;
  for (int kt = 0; kt < nk; ++kt) {
    const int k0 = kt << 4;
    float4 av = make_float4(0.f, 0.f, 0.f, 0.f);
    if (rowok) {
      const int k = k0 + lk;
      if (k < 128) av = *(const float4*)(A + (size_t)grow * 128 + k);
      else av = *(const float4*)(emb + (size_t)embrow * 32 + (k - 128));
    }
    As[lk + 0][lrow] = av.x;
    As[lk + 1][lrow] = av.y;
    As[lk + 2][lrow] = av.z;
    As[lk + 3][lrow] = av.w;
    {
      const float* wp = W + (size_t)(k0 + bk) * 128 + bc;
      float4 b0 = *(const float4*)(wp);
      float4 b1 = *(const float4*)(wp + 4);
      *(float4*)&Bs[bk][bc] = b0;
      *(float4*)&Bs[bk][bc + 4] = b1;
    }
    __syncthreads();
#pragma unroll
    for (int kk = 0; kk < 16; ++kk) {
      const float4 b = *(const float4*)&Bs[kk][tc];
      const float4 a0 = *(const float4*)&As[kk][tr];
      const float4 a1 = *(const float4*)&As[kk][tr + 4];
      const float ar[8] = {a0.x, a0.y, a0.z, a0.w, a1.x, a1.y, a1.z, a1.w};
      const float br[4] = {b.x, b.y, b.z, b.w};
#pragma unroll
      for (int r = 0; r < 8; ++r)
#pragma unroll
        for (int c = 0; c < 4; ++c) acc[r][c] = fmaf(ar[r], br[c], acc[r][c]);
    }
    __syncthreads();
  }
#pragma unroll
  for (int r = 0; r < 8; ++r) {
    const int gr = row0 + tr + r;
    if (gr < n) {
      float4 o = make_float4(acc[r][0], acc[r][1], acc[r][2], acc[r][3]);
      *(float4*)(out + (size_t)gr * 128 + tc) = o;
    }
  }
}

// ---------------- Aggregation: one wave per node, pull over CSR ----------------

__global__ __launch_bounds__(256) void agg_kernel(
    const float* __restrict__ hw, const int* __restrict__ rowptr,
    const int* __restrict__ ssrc, const float* __restrict__ wnorm,
    const float* __restrict__ dinv, const float* __restrict__ bias,
    float* __restrict__ out, int n) {
  const int wid = (blockIdx.x * blockDim.x + threadIdx.x) >> 6;
  const int lane = threadIdx.x & 63;
  if (wid >= n) return;
  const int start = rowptr[wid];
  const int end = rowptr[wid + 1];
  const float2* __restrict__ hw2 = (const float2*)hw;
  float ax = 0.f, ay = 0.f;
  for (int e = start; e < end; ++e) {
    const int s = ssrc[e];
    const float nm = wnorm[e];
    const float2 v = hw2[(size_t)s * 64 + lane];
    ax = fmaf(v.x, nm, ax);
    ay = fmaf(v.y, nm, ay);
  }
  const float di = dinv[wid];
  const float w = di * di;
  const float2 sv = hw2[(size_t)wid * 64 + lane];
  ax = fmaf(sv.x, w, ax);
  ay = fmaf(sv.y, w, ay);
  const float2 bb = ((const float2*)bias)[lane];
  float ox = ax + bb.x, oy = ay + bb.y;
  float2 o;
  o.x = ox > 0.f ? ox : 0.f;
  o.y = oy > 0.f ? oy : 0.f;
  ((float2*)out)[(size_t)wid * 64 + lane] = o;
}

// ---------------- Pool: segment max (contiguous segments of NPG rows) ----------------

__global__ __launch_bounds__(128) void pool_kernel(const float* __restrict__ z,
                                                   float* __restrict__ pool, int npg) {
  const int g = blockIdx.x;
  const int c = threadIdx.x;
  const float* base = z + (size_t)g * npg * 128;
  float m = -INFINITY;
  for (int r = 0; r < npg; ++r) m = fmaxf(m, base[(size_t)r * 128 + c]);
  pool[(size_t)g * 128 + c] = m;
}

// ---------------- Head MLP: one block (128 threads) per graph ----------------

__global__ __launch_bounds__(128) void final_kernel(
    const float* __restrict__ z, const float* __restrict__ pool,
    const int* __restrict__ tloc, const int* __restrict__ ptr,
    const float* __restrict__ Wm1, const float* __restrict__ bm1,
    const float* __restrict__ Wm2, const float* __restrict__ bm2,
    float* __restrict__ out) {
  __shared__ float feats[640];
  __shared__ float hid[128];
  const int g = blockIdx.x;
  const int t = threadIdx.x;
  const int base = ptr[g];
  const int u = base + tloc[2 * g];
  const int v = base + tloc[2 * g + 1];
  const float hu = z[(size_t)u * 128 + t];
  const float hv = z[(size_t)v * 128 + t];
  feats[t] = hu;
  feats[128 + t] = hv;
  feats[256 + t] = fabsf(hu - hv);
  feats[384 + t] = hu * hv;
  feats[512 + t] = pool[(size_t)g * 128 + t];
  __syncthreads();
  float acc = bm1[t];
#pragma unroll 8
  for (int k = 0; k < 640; ++k) acc = fmaf(feats[k], Wm1[(size_t)k * 128 + t], acc);
  hid[t] = acc > 0.f ? acc : 0.f;
  __syncthreads();
  if (t < 2) {
    float a = bm2[t];
    for (int j = 0; j < 128; ++j) a = fmaf(hid[j], Wm2[j * 2 + t], a);
    out[g * 2 + t] = a;
  }
}

// ---------------- launch ----------------

extern "C" void kernel_launch(void* const* d_in, const int* in_sizes, int n_in,
                              void* d_out, int out_size, void* d_ws, size_t ws_size,
                              hipStream_t stream) {
  const float* x   = (const float*)d_in[0];
  const float* emb = (const float*)d_in[1];
  const float* W1  = (const float*)d_in[2];
  const float* b1  = (const float*)d_in[3];
  const float* W2  = (const float*)d_in[4];
  const float* b2  = (const float*)d_in[5];
  const float* Wm1 = (const float*)d_in[6];
  const float* bm1 = (const float*)d_in[7];
  const float* Wm2 = (const float*)d_in[8];
  const float* bm2 = (const float*)d_in[9];
  const int* eidx  = (const int*)d_in[10];
  const int* drnl  = (const int*)d_in[11];
  const int* tloc  = (const int*)d_in[13];
  const int* ptr   = (const int*)d_in[14];
  float* out = (float*)d_out;

  const int N = in_sizes[11];
  const int E = in_sizes[10] / 2;
  const int G = in_sizes[13] / 2;
  const int NPG = N / G;
  const int* srcp = eidx;
  const int* dstp = eidx + E;

  char* w = (char*)d_ws;
  size_t o = 0;
  auto alloc = [&](size_t bytes) {
    void* p = w + o;
    o = align_up(o + bytes, 256);
    return p;
  };
  int*   rowptr = (int*)alloc((size_t)(N + 1) * 4);
  int*   cnt    = (int*)alloc((size_t)N * 4);
  int*   bsum   = (int*)alloc(4096);
  float* dinv   = (float*)alloc((size_t)N * 4);
  int*   ssrc   = (int*)alloc((size_t)E * 4);
  float* wnorm  = (float*)alloc((size_t)E * 4);
  float* hw     = (float*)alloc((size_t)N * 128 * 4);
  float* zb     = (float*)alloc((size_t)N * 128 * 4);
  float* poolb  = (float*)alloc((size_t)G * 128 * 4);

  const int nbN = (N + 255) / 256;
  const int nbE = (E + 255) / 256;

  hipMemsetAsync(cnt, 0, (size_t)N * 4, stream);
  hist_kernel<<<nbE, 256, 0, stream>>>(dstp, cnt, E);
  scanA_kernel<<<nbN, 256, 0, stream>>>(cnt, rowptr, bsum, N);
  scanB_kernel<<<1, 512, 0, stream>>>(bsum, nbN);
  scanC_kernel<<<nbN, 256, 0, stream>>>(rowptr, bsum, N, E);
  dinv_kernel<<<nbN, 256, 0, stream>>>(rowptr, dinv, N);
  hipMemsetAsync(cnt, 0, (size_t)N * 4, stream);
  fill_kernel<<<nbE, 256, 0, stream>>>(srcp, dstp, rowptr, cnt, dinv, ssrc, wnorm, E);

  gemm_kernel<<<(N + 63) / 64, 256, 0, stream>>>(x, emb, drnl, W1, hw, N, 160);
  agg_kernel<<<(N * 64 + 255) / 256, 256, 0, stream>>>(hw, rowptr, ssrc, wnorm, dinv, b1, zb, N);
  gemm_kernel<<<(N + 63) / 64, 256, 0, stream>>>(zb, emb, drnl, W2, hw, N, 128);
  agg_kernel<<<(N * 64 + 255) / 256, 256, 0, stream>>>(hw, rowptr, ssrc, wnorm, dinv, b2, zb, N);
  pool_kernel<<<G, 128, 0, stream>>>(zb, poolb, NPG);
  final_kernel<<<G, 128, 0, stream>>>(zb, poolb, tloc, ptr, Wm1, bm1, Wm2, bm2, out);
}

// Round 2
// 554.450 us; speedup vs baseline: 1.2365x; 1.2365x over previous
//
#include <hip/hip_runtime.h>
#include <hip/hip_bf16.h>
#include <math.h>

static inline size_t align_up(size_t x, size_t a) { return (x + a - 1) / a * a; }

// ---------------- CSR build ----------------

__global__ void hist_kernel(const int* __restrict__ dst, int* __restrict__ cnt, int e) {
  int i = blockIdx.x * blockDim.x + threadIdx.x;
  if (i < e) atomicAdd(&cnt[dst[i]], 1);
}

__global__ __launch_bounds__(256) void scanA_kernel(const int* __restrict__ cnt,
                                                    int* __restrict__ excl,
                                                    int* __restrict__ bsum, int n) {
  __shared__ int sm[256];
  int gi = blockIdx.x * 256 + threadIdx.x;
  int v = (gi < n) ? cnt[gi] : 0;
  sm[threadIdx.x] = v;
  __syncthreads();
  for (int off = 1; off < 256; off <<= 1) {
    int x = (threadIdx.x >= off) ? sm[threadIdx.x - off] : 0;
    __syncthreads();
    sm[threadIdx.x] += x;
    __syncthreads();
  }
  if (gi < n) excl[gi] = sm[threadIdx.x] - v;
  if (threadIdx.x == 255) bsum[blockIdx.x] = sm[255];
}

__global__ __launch_bounds__(512) void scanB_kernel(int* __restrict__ bsum, int nb) {
  __shared__ int sm[512];
  const int t = threadIdx.x;
  int v = (t < nb) ? bsum[t] : 0;
  sm[t] = v;
  __syncthreads();
  for (int off = 1; off < 512; off <<= 1) {
    int x = (t >= off) ? sm[t - off] : 0;
    __syncthreads();
    sm[t] += x;
    __syncthreads();
  }
  if (t < nb) bsum[t] = sm[t] - v;  // exclusive block offsets
}

__global__ void scanC_kernel(int* __restrict__ rowptr, const int* __restrict__ bsum,
                             int n, int e) {
  int gi = blockIdx.x * 256 + threadIdx.x;
  if (gi < n) rowptr[gi] += bsum[blockIdx.x];
  if (gi == 0) rowptr[n] = e;
}

__global__ void dinv_kernel(const int* __restrict__ rowptr, float* __restrict__ dinv, int n) {
  int gi = blockIdx.x * blockDim.x + threadIdx.x;
  if (gi < n) dinv[gi] = rsqrtf((float)(rowptr[gi + 1] - rowptr[gi] + 1));
}

__global__ void fill_kernel(const int* __restrict__ src, const int* __restrict__ dst,
                            const int* __restrict__ rowptr, int* __restrict__ cur,
                            const float* __restrict__ dinv, int* __restrict__ ssrc,
                            float* __restrict__ wnorm, int e) {
  int i = blockIdx.x * blockDim.x + threadIdx.x;
  if (i < e) {
    int d = dst[i];
    int s = src[i];
    int pos = rowptr[d] + atomicAdd(&cur[d], 1);
    ssrc[pos] = s;
    wnorm[pos] = dinv[s] * dinv[d];
  }
}

// ---------------- GEMM: out[N][128] = A(concat x|emb[drnl] or z)[N][K] @ W[K][128] ----------------

__global__ __launch_bounds__(256) void gemm_kernel(
    const float* __restrict__ A, const float* __restrict__ emb,
    const int* __restrict__ drnl, const float* __restrict__ W,
    float* __restrict__ out, int n, int K) {
  __shared__ float As[16][68];   // k-major, padded
  __shared__ float Bs[16][128];
  const int tid = threadIdx.x;
  const int row0 = blockIdx.x * 64;
  const int tc = (tid & 31) * 4;   // col base
  const int tr = (tid >> 5) * 8;   // row base

  float acc[8][4];
#pragma unroll
  for (int i = 0; i < 8; ++i)
#pragma unroll
    for (int j = 0; j < 4; ++j) acc[i][j] = 0.f;

  const int lrow = tid >> 2;        // 0..63 — A-load row
  const int lk = (tid & 3) * 4;     // 0,4,8,12 — A-load k base
  const int grow = row0 + lrow;
  const bool rowok = grow < n;
  int embrow = 0;
  if (K > 128 && rowok) embrow = drnl[grow];

  const int bk = tid >> 4;          // 0..15 — B-load row
  const int bc = (tid & 15) * 8;    // B-load col base

  const int nk = K >> 4;
  for (int kt = 0; kt < nk; ++kt) {
    const int k0 = kt << 4;
    float4 av = make_float4(0.f, 0.f, 0.f, 0.f);
    if (rowok) {
      const int k = k0 + lk;
      if (k < 128) av = *(const float4*)(A + (size_t)grow * 128 + k);
      else av = *(const float4*)(emb + (size_t)embrow * 32 + (k - 128));
    }
    As[lk + 0][lrow] = av.x;
    As[lk + 1][lrow] = av.y;
    As[lk + 2][lrow] = av.z;
    As[lk + 3][lrow] = av.w;
    {
      const float* wp = W + (size_t)(k0 + bk) * 128 + bc;
      float4 b0 = *(const float4*)(wp);
      float4 b1 = *(const float4*)(wp + 4);
      *(float4*)&Bs[bk][bc] = b0;
      *(float4*)&Bs[bk][bc + 4] = b1;
    }
    __syncthreads();
#pragma unroll
    for (int kk = 0; kk < 16; ++kk) {
      const float4 b = *(const float4*)&Bs[kk][tc];
      const float4 a0 = *(const float4*)&As[kk][tr];
      const float4 a1 = *(const float4*)&As[kk][tr + 4];
      const float ar[8] = {a0.x, a0.y, a0.z, a0.w, a1.x, a1.y, a1.z, a1.w};
      const float br[4] = {b.x, b.y, b.z, b.w};
#pragma unroll
      for (int r = 0; r < 8; ++r)
#pragma unroll
        for (int c = 0; c < 4; ++c) acc[r][c] = fmaf(ar[r], br[c], acc[r][c]);
    }
    __syncthreads();
  }
#pragma unroll
  for (int r = 0; r < 8; ++r) {
    const int gr = row0 + tr + r;
    if (gr < n) {
      float4 o = make_float4(acc[r][0], acc[r][1], acc[r][2], acc[r][3]);
      *(float4*)(out + (size_t)gr * 128 + tc) = o;
    }
  }
}

// ---------------- Aggregation: one wave per node, pull over CSR ----------------
// Unrolled x4: 4 independent 512B gathers in flight per wave (MLP hiding).

__global__ __launch_bounds__(256) void agg_kernel(
    const float* __restrict__ hw, const int* __restrict__ rowptr,
    const int* __restrict__ ssrc, const float* __restrict__ wnorm,
    const float* __restrict__ dinv, const float* __restrict__ bias,
    float* __restrict__ out, int n) {
  const int widx = (blockIdx.x * blockDim.x + threadIdx.x) >> 6;
  if (widx >= n) return;
  const int wid = __builtin_amdgcn_readfirstlane(widx);
  const int lane = threadIdx.x & 63;
  const int start = rowptr[wid];
  const int end = rowptr[wid + 1];
  const float2* __restrict__ hw2 = (const float2*)hw;
  float ax = 0.f, ay = 0.f;
  int e = start;
  for (; e + 4 <= end; e += 4) {
    const int s0 = ssrc[e + 0];
    const int s1 = ssrc[e + 1];
    const int s2 = ssrc[e + 2];
    const int s3 = ssrc[e + 3];
    const float n0 = wnorm[e + 0];
    const float n1 = wnorm[e + 1];
    const float n2 = wnorm[e + 2];
    const float n3 = wnorm[e + 3];
    const float2 v0 = hw2[(size_t)s0 * 64 + lane];
    const float2 v1 = hw2[(size_t)s1 * 64 + lane];
    const float2 v2 = hw2[(size_t)s2 * 64 + lane];
    const float2 v3 = hw2[(size_t)s3 * 64 + lane];
    ax = fmaf(v0.x, n0, ax); ay = fmaf(v0.y, n0, ay);
    ax = fmaf(v1.x, n1, ax); ay = fmaf(v1.y, n1, ay);
    ax = fmaf(v2.x, n2, ax); ay = fmaf(v2.y, n2, ay);
    ax = fmaf(v3.x, n3, ax); ay = fmaf(v3.y, n3, ay);
  }
  for (; e < end; ++e) {
    const int s = ssrc[e];
    const float nm = wnorm[e];
    const float2 v = hw2[(size_t)s * 64 + lane];
    ax = fmaf(v.x, nm, ax);
    ay = fmaf(v.y, nm, ay);
  }
  const float di = dinv[wid];
  const float w = di * di;
  const float2 sv = hw2[(size_t)wid * 64 + lane];
  ax = fmaf(sv.x, w, ax);
  ay = fmaf(sv.y, w, ay);
  const float2 bb = ((const float2*)bias)[lane];
  float ox = ax + bb.x, oy = ay + bb.y;
  float2 o;
  o.x = ox > 0.f ? ox : 0.f;
  o.y = oy > 0.f ? oy : 0.f;
  ((float2*)out)[(size_t)wid * 64 + lane] = o;
}

// ---------------- Pool: segment max (contiguous segments of NPG rows) ----------------

__global__ __launch_bounds__(128) void pool_kernel(const float* __restrict__ z,
                                                   float* __restrict__ pool, int npg) {
  const int g = blockIdx.x;
  const int c = threadIdx.x;
  const float* base = z + (size_t)g * npg * 128;
  float m = -INFINITY;
  for (int r = 0; r < npg; ++r) m = fmaxf(m, base[(size_t)r * 128 + c]);
  pool[(size_t)g * 128 + c] = m;
}

// ---------------- Head MLP: one block (128 threads) per graph ----------------

__global__ __launch_bounds__(128) void final_kernel(
    const float* __restrict__ z, const float* __restrict__ pool,
    const int* __restrict__ tloc, const int* __restrict__ ptr,
    const float* __restrict__ Wm1, const float* __restrict__ bm1,
    const float* __restrict__ Wm2, const float* __restrict__ bm2,
    float* __restrict__ out) {
  __shared__ float feats[640];
  __shared__ float hid[128];
  const int g = blockIdx.x;
  const int t = threadIdx.x;
  const int base = ptr[g];
  const int u = base + tloc[2 * g];
  const int v = base + tloc[2 * g + 1];
  const float hu = z[(size_t)u * 128 + t];
  const float hv = z[(size_t)v * 128 + t];
  feats[t] = hu;
  feats[128 + t] = hv;
  feats[256 + t] = fabsf(hu - hv);
  feats[384 + t] = hu * hv;
  feats[512 + t] = pool[(size_t)g * 128 + t];
  __syncthreads();
  float acc = bm1[t];
#pragma unroll 8
  for (int k = 0; k < 640; ++k) acc = fmaf(feats[k], Wm1[(size_t)k * 128 + t], acc);
  hid[t] = acc > 0.f ? acc : 0.f;
  __syncthreads();
  if (t < 2) {
    float a = bm2[t];
    for (int j = 0; j < 128; ++j) a = fmaf(hid[j], Wm2[j * 2 + t], a);
    out[g * 2 + t] = a;
  }
}

// ---------------- launch ----------------

extern "C" void kernel_launch(void* const* d_in, const int* in_sizes, int n_in,
                              void* d_out, int out_size, void* d_ws, size_t ws_size,
                              hipStream_t stream) {
  const float* x   = (const float*)d_in[0];
  const float* emb = (const float*)d_in[1];
  const float* W1  = (const float*)d_in[2];
  const float* b1  = (const float*)d_in[3];
  const float* W2  = (const float*)d_in[4];
  const float* b2  = (const float*)d_in[5];
  const float* Wm1 = (const float*)d_in[6];
  const float* bm1 = (const float*)d_in[7];
  const float* Wm2 = (const float*)d_in[8];
  const float* bm2 = (const float*)d_in[9];
  const int* eidx  = (const int*)d_in[10];
  const int* drnl  = (const int*)d_in[11];
  const int* tloc  = (const int*)d_in[13];
  const int* ptr   = (const int*)d_in[14];
  float* out = (float*)d_out;

  const int N = in_sizes[11];
  const int E = in_sizes[10] / 2;
  const int G = in_sizes[13] / 2;
  const int NPG = N / G;
  const int* srcp = eidx;
  const int* dstp = eidx + E;

  char* w = (char*)d_ws;
  size_t o = 0;
  auto alloc = [&](size_t bytes) {
    void* p = w + o;
    o = align_up(o + bytes, 256);
    return p;
  };
  int*   rowptr = (int*)alloc((size_t)(N + 1) * 4);
  int*   cnt    = (int*)alloc((size_t)N * 4);
  int*   bsum   = (int*)alloc(4096);
  float* dinv   = (float*)alloc((size_t)N * 4);
  int*   ssrc   = (int*)alloc((size_t)E * 4);
  float* wnorm  = (float*)alloc((size_t)E * 4);
  float* hw     = (float*)alloc((size_t)N * 128 * 4);
  float* zb     = (float*)alloc((size_t)N * 128 * 4);
  float* poolb  = (float*)alloc((size_t)G * 128 * 4);

  const int nbN = (N + 255) / 256;
  const int nbE = (E + 255) / 256;

  hipMemsetAsync(cnt, 0, (size_t)N * 4, stream);
  hist_kernel<<<nbE, 256, 0, stream>>>(dstp, cnt, E);
  scanA_kernel<<<nbN, 256, 0, stream>>>(cnt, rowptr, bsum, N);
  scanB_kernel<<<1, 512, 0, stream>>>(bsum, nbN);
  scanC_kernel<<<nbN, 256, 0, stream>>>(rowptr, bsum, N, E);
  dinv_kernel<<<nbN, 256, 0, stream>>>(rowptr, dinv, N);
  hipMemsetAsync(cnt, 0, (size_t)N * 4, stream);
  fill_kernel<<<nbE, 256, 0, stream>>>(srcp, dstp, rowptr, cnt, dinv, ssrc, wnorm, E);

  gemm_kernel<<<(N + 63) / 64, 256, 0, stream>>>(x, emb, drnl, W1, hw, N, 160);
  agg_kernel<<<(N * 64 + 255) / 256, 256, 0, stream>>>(hw, rowptr, ssrc, wnorm, dinv, b1, zb, N);
  gemm_kernel<<<(N + 63) / 64, 256, 0, stream>>>(zb, emb, drnl, W2, hw, N, 128);
  agg_kernel<<<(N * 64 + 255) / 256, 256, 0, stream>>>(hw, rowptr, ssrc, wnorm, dinv, b2, zb, N);
  pool_kernel<<<G, 128, 0, stream>>>(zb, poolb, NPG);
  final_kernel<<<G, 128, 0, stream>>>(zb, poolb, tloc, ptr, Wm1, bm1, Wm2, bm2, out);
}